// Round 5
// baseline (1335.209 us; speedup 1.0000x reference)
//
#include <hip/hip_runtime.h>

#define A_DIM 64
#define B_DIM 128
#define E 128
#define NG 50
#define NROW (A_DIM*A_DIM*B_DIM)   // 524288
#define TR 128                     // rows per block
#define KS 136                     // xa row stride (shorts), 16B-aligned rows
#define WS 40                      // wc row stride (shorts) — 32 data + 8 pad (DMA 5-slot trick)
#define SMS 72                     // smb row stride (shorts)
#define BR_STRIDE 147456           // shorts per branch in prepped-weight region
#define RBF_OFF 131072             // short offset of rbf planes within a branch

using bf16x8  = __bf16 __attribute__((ext_vector_type(8)));
using bf16x2  = __bf16 __attribute__((ext_vector_type(2)));
using short8v = short __attribute__((ext_vector_type(8)));
using f32x4   = float __attribute__((ext_vector_type(4)));

__device__ __forceinline__ float silu_f(float x) {
  return x * __builtin_amdgcn_rcpf(1.0f + __expf(-x));
}

__device__ __forceinline__ unsigned short bf16_rne(float v) {
  unsigned u = __float_as_uint(v);
  return (unsigned short)((u + 0x7FFFu + ((u >> 16) & 1u)) >> 16);
}

// pack two floats -> two bf16 (RNE). HW op on gfx950, manual fallback otherwise.
__device__ __forceinline__ unsigned pk_bf16(float a, float b) {
#if __has_builtin(__builtin_amdgcn_cvt_pk_bf16_f32)
  bf16x2 r = __builtin_amdgcn_cvt_pk_bf16_f32(a, b);
  return __builtin_bit_cast(unsigned, r);
#else
  return ((unsigned)bf16_rne(b) << 16) | (unsigned)bf16_rne(a);
#endif
}

__device__ __forceinline__ void split_fast(float v, unsigned short& h, unsigned short& l) {
  unsigned p = pk_bf16(v, v);
  h = (unsigned short)p;
  float fh = __uint_as_float(p << 16);
  unsigned q2 = pk_bf16(v - fh, v - fh);
  l = (unsigned short)q2;
}

// Stage one W k-chunk (2 planes x 128 rows x 32 k, rows padded to WS=40 shorts).
// Per-thread slot mapping precomputed in pre_* (pn=row, ps8=short-offset, pl=lds
// short-offset (uniform), pp=plane).
__device__ __forceinline__ void stage(const short* gbase, int pstride, int kshift,
                                      int k0, short* lds,
                                      const int* pn, const int* ps8,
                                      const int* pl, const int* pp) {
  #pragma unroll
  for (int i = 0; i < 5; ++i) {
    const short* gp = gbase + pp[i] * pstride + (pn[i] << kshift) + k0 + ps8[i];
    short* lp = lds + pl[i];                 // wave-uniform; HW adds lane*16B
    __builtin_amdgcn_global_load_lds(
        (const __attribute__((address_space(1))) void*)gp,
        (__attribute__((address_space(3))) void*)lp, 16, 0, 0);
  }
}

// One K=32 step: acc[rt][ct] += split-fp32( x[wave's 64 rows] @ W[wave's 64 cols] )
__device__ __forceinline__ void gemm_step(const short* xhi, const short* xlo, int xstr,
                                          const short* wcb, int kcol,
                                          f32x4 acc[4][4], int rw0, int cw0,
                                          int m, int o) {
  bf16x8 bh[4], bl[4];
  #pragma unroll
  for (int ct = 0; ct < 4; ++ct) {
    int ng = cw0 + ct * 16 + m;
    bh[ct] = __builtin_bit_cast(bf16x8, *(const short8v*)(wcb + ng * WS + o * 8));
    bl[ct] = __builtin_bit_cast(bf16x8, *(const short8v*)(wcb + 128 * WS + ng * WS + o * 8));
  }
  #pragma unroll
  for (int rt = 0; rt < 4; ++rt) {
    int row = rw0 + rt * 16 + m;
    bf16x8 ah = __builtin_bit_cast(bf16x8, *(const short8v*)(xhi + row * xstr + kcol + o * 8));
    bf16x8 al = __builtin_bit_cast(bf16x8, *(const short8v*)(xlo + row * xstr + kcol + o * 8));
    #pragma unroll
    for (int ct = 0; ct < 4; ++ct) {
      acc[rt][ct] = __builtin_amdgcn_mfma_f32_16x16x32_bf16(al, bh[ct], acc[rt][ct], 0, 0, 0);
      acc[rt][ct] = __builtin_amdgcn_mfma_f32_16x16x32_bf16(ah, bl[ct], acc[rt][ct], 0, 0, 0);
      acc[rt][ct] = __builtin_amdgcn_mfma_f32_16x16x32_bf16(ah, bh[ct], acc[rt][ct], 0, 0, 0);
    }
  }
}

// Transpose + bf16 hi/lo split of all weight matrices into workspace.
__global__ __launch_bounds__(256) void prep_weights(
    const float* __restrict__ eWin, const float* __restrict__ eWh,
    const float* __restrict__ eWout, const float* __restrict__ erbf,
    const float* __restrict__ fWin, const float* __restrict__ fWh,
    const float* __restrict__ fWout, const float* __restrict__ frbf,
    short* __restrict__ S)
{
  int o = blockIdx.x * 256 + threadIdx.x;
  if (o >= 2 * 73728) return;
  int br = (o >= 73728) ? 1 : 0;
  int r = o - br * 73728;
  short* base = S + br * BR_STRIDE;
  float v; int dh;
  int lo_off;
  if (r < 65536) {
    int lay = r >> 14, idx = r & 16383, n = idx >> 7, k = idx & 127;
    const float* W = (lay == 0) ? (br ? fWin : eWin)
                   : (lay == 3) ? (br ? fWout : eWout)
                   : ((br ? fWh : eWh) + (lay - 1) * 16384);
    v = W[k * 128 + n];
    dh = lay * 32768 + n * 128 + k; lo_off = 16384;
  } else {
    int rr = r - 65536;                 // 0..8191
    int n = rr >> 6, k = rr & 63;
    v = (k < NG) ? (br ? frbf : erbf)[k * 128 + n] : 0.0f;
    dh = RBF_OFF + n * 64 + k; lo_off = 8192;
  }
  unsigned short h, l;
  unsigned ph = pk_bf16(v, v);
  h = (unsigned short)ph;
  float fh = __uint_as_float(ph << 16);
  l = (unsigned short)pk_bf16(v - fh, v - fh);
  base[dh] = (short)h;
  base[dh + lo_off] = (short)l;
}

__global__ __launch_bounds__(256, 1) void fused_main(
    const float* __restrict__ T, const float* __restrict__ mask,
    const float* __restrict__ dist,
    const float* __restrict__ ebin, const float* __restrict__ ebh,
    const float* __restrict__ ebout, const float* __restrict__ ehead,
    const float* __restrict__ fbin, const float* __restrict__ fbh,
    const float* __restrict__ fbout, const float* __restrict__ fhead,
    const short* __restrict__ S,
    float* __restrict__ em, float* __restrict__ fm)
{
  __shared__ short xa[2 * TR * KS];        // 69632 B (hi plane, lo plane)
  __shared__ short wc[2][2 * 128 * WS];    // 40960 B  -> 110592 B total (1 block/CU)

  const int t = threadIdx.x;
  const int wave = t >> 6, lane = t & 63;
  const int q = lane >> 4, n16 = lane & 15;
  const int m = n16, o = q;
  const int rw0 = (wave & 1) * 64;         // wave's row half
  const int cw0 = (wave >> 1) * 64;        // wave's col half
  const int br = blockIdx.x & 1;
  const long tile = blockIdx.x >> 1;
  const long r0g = tile * TR;

  const short* Wp = S + br * BR_STRIDE;
  const float* bin  = br ? fbin : ebin;
  const float* bh_  = br ? fbh : ebh;
  const float* bout = br ? fbout : ebout;
  const float* head = br ? fhead : ehead;
  float* outw = br ? fm : em;

  short* xahi = xa;
  short* xalo = xa + TR * KS;

  const float stepv = 12.0f / 49.0f;
  const float coeff = -0.5f / (stepv * stepv);

  // ---- precompute DMA slot mapping (wave-uniform except global row/slot) ----
  int pre_n[5], pre_s8[5], pre_lds[5], pre_p[5];
  #pragma unroll
  for (int i = 0; i < 5; ++i) {
    int g = wave + 4 * i;                  // 0..19
    int p = (g >= 10) ? 1 : 0;
    int gg = g - 10 * p;
    int slin = gg * 64 + lane;
    int n = (int)((unsigned)slin / 5u);
    int s = slin - 5 * n; if (s > 3) s = 3;
    pre_n[i] = n; pre_s8[i] = s * 8;
    pre_lds[i] = p * (128 * WS) + gg * 512;
    pre_p[i] = p;
  }

  // chunk 0 (lay0, k 0..31) DMA in flight during T staging
  stage(Wp, 16384, 7, 0, wc[0], pre_n, pre_s8, pre_lds, pre_p);

  // ---- T tile (128 rows x 128) -> xa hi/lo planes ----
  {
    int row = t >> 1, cs = (t & 1) * 64;
    const float4* Tp = (const float4*)(T + (r0g + row) * E + cs);
    short* ph = xahi + row * KS + cs;
    short* pl = xalo + row * KS + cs;
    #pragma unroll
    for (int j = 0; j < 16; ++j) {
      float4 v = Tp[j];
      unsigned h01 = pk_bf16(v.x, v.y);
      unsigned h23 = pk_bf16(v.z, v.w);
      float r0 = v.x - __uint_as_float(h01 << 16);
      float r1 = v.y - __uint_as_float(h01 & 0xFFFF0000u);
      float r2 = v.z - __uint_as_float(h23 << 16);
      float r3 = v.w - __uint_as_float(h23 & 0xFFFF0000u);
      unsigned l01 = pk_bf16(r0, r1);
      unsigned l23 = pk_bf16(r2, r3);
      *(uint2*)(ph + j * 4) = make_uint2(h01, h23);
      *(uint2*)(pl + j * 4) = make_uint2(l01, l23);
    }
  }

  float xres[4][4][4];
  f32x4 acc[4][4];

  // ---- 4 dense layers x 4 K-chunks, DMA double-buffered ----
  #pragma unroll 1
  for (int lay = 0; lay < 4; ++lay) {
    const float* bg = (lay == 0) ? bin : (lay == 3) ? bout : (bh_ + (lay - 1) * E);
    float bv[4];
    #pragma unroll
    for (int ct = 0; ct < 4; ++ct) bv[ct] = bg[cw0 + ct * 16 + n16];
    #pragma unroll
    for (int rt = 0; rt < 4; ++rt)
      #pragma unroll
      for (int ct = 0; ct < 4; ++ct)
        acc[rt][ct] = (f32x4){bv[ct], bv[ct], bv[ct], bv[ct]};

    #pragma unroll 1
    for (int ch = 0; ch < 4; ++ch) {
      __syncthreads();               // drains this chunk's DMA + orders xa writes
      int ci = lay * 4 + ch;
      if (ci < 15) {
        int cn = ci + 1;
        stage(Wp + (cn >> 2) * 32768, 16384, 7, (cn & 3) * 32,
              wc[cn & 1], pre_n, pre_s8, pre_lds, pre_p);
      } else {                       // ci==15 reads wc[1]; stage rbf chunk0 -> wc[0]
        stage(Wp + RBF_OFF, 8192, 6, 0, wc[0], pre_n, pre_s8, pre_lds, pre_p);
      }
      gemm_step(xahi, xalo, KS, wc[ci & 1], ch * 32, acc, rw0, cw0, m, o);
    }
    if (lay < 3) {
      __syncthreads();               // all xa reads of this layer done
      #pragma unroll
      for (int rt = 0; rt < 4; ++rt)
        #pragma unroll
        for (int ct = 0; ct < 4; ++ct) {
          int col = cw0 + ct * 16 + n16;
          #pragma unroll
          for (int i = 0; i < 4; ++i) {
            float v = silu_f(acc[rt][ct][i]);
            if (lay > 0) v += xres[rt][ct][i];
            xres[rt][ct][i] = v;
            unsigned short h, l; split_fast(v, h, l);
            int row = rw0 + rt * 16 + q * 4 + i;
            xahi[row * KS + col] = (short)h;
            xalo[row * KS + col] = (short)l;
          }
        }
    }
  }
  // acc now holds feat (Wout layer, bias included, no activation)

  __syncthreads();                   // wc[1]/xa reads done; rbf chunk0 DMA drained
  stage(Wp + RBF_OFF, 8192, 6, 32, wc[1], pre_n, pre_s8, pre_lds, pre_p);

  // ---- smeared gaussians -> smb hi/lo planes (overlay xa region) ----
  short* smhi = xa;
  short* smlo = xa + TR * SMS;
  {
    int row = t >> 1, ks0 = (t & 1) * 32;
    float d = dist[r0g + row];
    short* ph = smhi + row * SMS + ks0;
    short* pl = smlo + row * SMS + ks0;
    #pragma unroll
    for (int j = 0; j < 8; ++j) {
      float vv[4];
      #pragma unroll
      for (int jj = 0; jj < 4; ++jj) {
        int k = ks0 + j * 4 + jj;
        float dd = d - (float)k * stepv;
        vv[jj] = (k < NG) ? __expf(coeff * dd * dd) : 0.0f;
      }
      unsigned h01 = pk_bf16(vv[0], vv[1]);
      unsigned h23 = pk_bf16(vv[2], vv[3]);
      float r0 = vv[0] - __uint_as_float(h01 << 16);
      float r1 = vv[1] - __uint_as_float(h01 & 0xFFFF0000u);
      float r2 = vv[2] - __uint_as_float(h23 << 16);
      float r3 = vv[3] - __uint_as_float(h23 & 0xFFFF0000u);
      unsigned l01 = pk_bf16(r0, r1);
      unsigned l23 = pk_bf16(r2, r3);
      *(uint2*)(ph + j * 4) = make_uint2(h01, h23);
      *(uint2*)(pl + j * 4) = make_uint2(l01, l23);
    }
  }
  float hv[4];
  #pragma unroll
  for (int ct = 0; ct < 4; ++ct) hv[ct] = head[cw0 + ct * 16 + n16];

  f32x4 acc2[4][4];
  #pragma unroll
  for (int rt = 0; rt < 4; ++rt)
    #pragma unroll
    for (int ct = 0; ct < 4; ++ct)
      acc2[rt][ct] = (f32x4){0.f, 0.f, 0.f, 0.f};

  __syncthreads();                   // smb visible + rbf chunk0/1 DMA drained
  gemm_step(smhi, smlo, SMS, wc[0], 0,  acc2, rw0, cw0, m, o);
  gemm_step(smhi, smlo, SMS, wc[1], 32, acc2, rw0, cw0, m, o);

  // ---- head dot: per-row partials, cross-(col-half) reduce via LDS ----
  __syncthreads();                   // wc reads done before part overlay
  float* part = (float*)wc;          // 2 x 128 floats
  #pragma unroll
  for (int rt = 0; rt < 4; ++rt)
    #pragma unroll
    for (int i = 0; i < 4; ++i) {
      float p = 0.0f;
      #pragma unroll
      for (int ct = 0; ct < 4; ++ct)
        p += acc[rt][ct][i] * acc2[rt][ct][i] * hv[ct];
      p += __shfl_xor(p, 1); p += __shfl_xor(p, 2);
      p += __shfl_xor(p, 4); p += __shfl_xor(p, 8);
      if (n16 == 0) part[(wave >> 1) * 128 + rw0 + rt * 16 + q * 4 + i] = p;
    }
  __syncthreads();
  if (t < TR) {
    float pr = part[t] + part[128 + t];
    outw[r0g + t] = pr * mask[r0g + t];
  }
}

__global__ __launch_bounds__(256) void energy_kernel(const float* __restrict__ em,
                                                     float* __restrict__ out) {
  __shared__ float red[256];
  int b = blockIdx.x, t = threadIdx.x;
  float s = 0.0f;
  for (int p = t; p < A_DIM * A_DIM; p += 256) s += em[(long)p * B_DIM + b];
  red[t] = s; __syncthreads();
  for (int off = 128; off > 0; off >>= 1) {
    if (t < off) red[t] += red[t + off];
    __syncthreads();
  }
  if (t == 0) out[b] = red[0] * (1.0f / 3600.0f);
}

__global__ __launch_bounds__(256) void forces_kernel(const float* __restrict__ fm,
                                                     const float* __restrict__ vh,
                                                     float* __restrict__ out) {
  int o = blockIdx.x * 256 + threadIdx.x;   // 24576 outputs = [j][b][c]
  if (o >= A_DIM * B_DIM * 3) return;
  int c = o % 3;
  int b = (o / 3) % B_DIM;
  int j = o / (B_DIM * 3);
  float s = 0.0f;
  #pragma unroll 4
  for (int i = 0; i < A_DIM; ++i) {
    long row = ((long)(i * A_DIM + j)) * B_DIM + b;
    s += fm[row] * vh[row * 3 + c];
  }
  out[B_DIM + o] = s * (1.0f / 60.0f);
}

extern "C" void kernel_launch(void* const* d_in, const int* in_sizes, int n_in,
                              void* d_out, int out_size, void* d_ws, size_t ws_size,
                              hipStream_t stream) {
  const float* T    = (const float*)d_in[0];
  const float* mask = (const float*)d_in[1];
  const float* dist = (const float*)d_in[2];
  const float* vh   = (const float*)d_in[3];
  const float* eWin = (const float*)d_in[4];
  const float* ebin = (const float*)d_in[5];
  const float* eWh  = (const float*)d_in[6];
  const float* ebh  = (const float*)d_in[7];
  const float* eWout= (const float*)d_in[8];
  const float* ebout= (const float*)d_in[9];
  const float* erbf = (const float*)d_in[10];
  const float* ehead= (const float*)d_in[11];
  const float* fWin = (const float*)d_in[12];
  const float* fbin = (const float*)d_in[13];
  const float* fWh  = (const float*)d_in[14];
  const float* fbh  = (const float*)d_in[15];
  const float* fWout= (const float*)d_in[16];
  const float* fbout= (const float*)d_in[17];
  const float* frbf = (const float*)d_in[18];
  const float* fhead= (const float*)d_in[19];

  float* em = (float*)d_ws;
  float* fm = em + NROW;
  short* S  = (short*)(fm + NROW);
  float* out = (float*)d_out;

  prep_weights<<<576, 256, 0, stream>>>(eWin, eWh, eWout, erbf,
                                        fWin, fWh, fWout, frbf, S);
  fused_main<<<2 * (NROW / TR), 256, 0, stream>>>(
      T, mask, dist,
      ebin, ebh, ebout, ehead,
      fbin, fbh, fbout, fhead,
      S, em, fm);
  energy_kernel<<<B_DIM, 256, 0, stream>>>(em, out);
  forces_kernel<<<(A_DIM * B_DIM * 3) / 256, 256, 0, stream>>>(fm, vh, out);
}